// Round 13
// baseline (185.873 us; speedup 1.0000x reference)
//
#include <hip/hip_runtime.h>

typedef __bf16 bf16x8 __attribute__((ext_vector_type(8)));
typedef float f32x4 __attribute__((ext_vector_type(4)));
typedef unsigned short ushort_t;
typedef unsigned int uint_t;

constexpr int S = 4096, DMODEL = 1024, NH = 16, HD = 64;
// softmax scale folded with log2(e): scores come out of QK^T already in log2 domain
#define QSCALE 0.18033688011112042f  // 0.125 * log2(e)

#if __has_builtin(__builtin_amdgcn_exp2f)
#define EXP2(x) __builtin_amdgcn_exp2f(x)
#else
#define EXP2(x) exp2f(x)
#endif

__device__ inline ushort_t f2bf(float f) {
  uint_t u = __builtin_bit_cast(uint_t, f);
  u = u + 0x7FFFu + ((u >> 16) & 1u);  // round-to-nearest-even
  return (ushort_t)(u >> 16);
}

__device__ inline ushort_t f2bf_hw(float f) {
  __bf16 h = (__bf16)f;  // v_cvt RNE on gfx950
  return __builtin_bit_cast(ushort_t, h);
}

__device__ inline void gl2lds16(const ushort_t* g, ushort_t* l) {
  __builtin_amdgcn_global_load_lds(
      (const __attribute__((address_space(1))) unsigned int*)g,
      (__attribute__((address_space(3))) unsigned int*)l, 16, 0, 0);
}

// ---------------- fp32 -> bf16 conversion ----------------
__global__ __launch_bounds__(256) void cvt_f32_bf16(const float* __restrict__ in,
                                                    ushort_t* __restrict__ out, int n4) {
  int i = blockIdx.x * 256 + threadIdx.x;
  if (i >= n4) return;
  float4 f = reinterpret_cast<const float4*>(in)[i];
  ushort4 o;
  o.x = f2bf(f.x); o.y = f2bf(f.y); o.z = f2bf(f.z); o.w = f2bf(f.w);
  reinterpret_cast<ushort4*>(out)[i] = o;
}

// ---------------- GEMM: C[M][N] = A[M][K] * B[N][K]^T (both row-major [rows][K], bf16) ----
template <int EPI>
__global__ __launch_bounds__(256) void gemm_bt(const ushort_t* __restrict__ A,
                                               const ushort_t* __restrict__ B,
                                               int M, int N, int K,
                                               float* __restrict__ Cf,
                                               ushort_t* __restrict__ qb,
                                               ushort_t* __restrict__ kb,
                                               ushort_t* __restrict__ vtb) {
  __shared__ ushort_t sA[128 * 64];
  __shared__ ushort_t sB[128 * 64];
  const int t = threadIdx.x;
  const int lane = t & 63, w = t >> 6;
  const int wr = w >> 1, wc = w & 1;
  const int lin = blockIdx.y * gridDim.x + blockIdx.x;
  const int cpx = (gridDim.x * gridDim.y) >> 3;
  const int swz = (lin & 7) * cpx + (lin >> 3);
  const int rA0 = (swz / gridDim.x) * 128, rB0 = (swz % gridDim.x) * 128;

  f32x4 acc[4][4];
#pragma unroll
  for (int m = 0; m < 4; ++m)
#pragma unroll
    for (int n = 0; n < 4; ++n) acc[m][n] = (f32x4){0.f, 0.f, 0.f, 0.f};

  const int srow = t >> 3;
  const int scol = (t & 7) * 8;
  const int ldsbase = w * 512;

  for (int k0 = 0; k0 < K; k0 += 64) {
#pragma unroll
    for (int i = 0; i < 4; ++i) {
      int r = i * 32 + srow;
      int kc = scol ^ ((r & 7) << 3);
      gl2lds16(&A[(size_t)(rA0 + r) * K + k0 + kc], &sA[i * 2048 + ldsbase]);
    }
#pragma unroll
    for (int i = 0; i < 4; ++i) {
      int r = i * 32 + srow;
      int kc = scol ^ ((r & 7) << 3);
      gl2lds16(&B[(size_t)(rB0 + r) * K + k0 + kc], &sB[i * 2048 + ldsbase]);
    }
    __syncthreads();
#pragma unroll
    for (int ks = 0; ks < 2; ++ks) {
      const int kk = ks * 32 + (lane >> 4) * 8;
      bf16x8 af[4], bfr[4];
#pragma unroll
      for (int m = 0; m < 4; ++m) {
        int row = wr * 64 + m * 16 + (lane & 15);
        af[m] = *(const bf16x8*)&sA[row * 64 + (kk ^ ((row & 7) << 3))];
      }
#pragma unroll
      for (int n = 0; n < 4; ++n) {
        int row = wc * 64 + n * 16 + (lane & 15);
        bfr[n] = *(const bf16x8*)&sB[row * 64 + (kk ^ ((row & 7) << 3))];
      }
#pragma unroll
      for (int m = 0; m < 4; ++m)
#pragma unroll
        for (int n = 0; n < 4; ++n)
          acc[m][n] = __builtin_amdgcn_mfma_f32_16x16x32_bf16(af[m], bfr[n], acc[m][n], 0, 0, 0);
    }
    __syncthreads();
  }

#pragma unroll
  for (int m = 0; m < 4; ++m)
#pragma unroll
    for (int n = 0; n < 4; ++n)
#pragma unroll
      for (int r = 0; r < 4; ++r) {
        int row = rA0 + wr * 64 + m * 16 + (lane >> 4) * 4 + r;
        int col = rB0 + wc * 64 + n * 16 + (lane & 15);
        float v = acc[m][n][r];
        if constexpr (EPI == 0) {
          Cf[(size_t)row * N + col] = v;
        } else {
          int t3 = col >> 10, h = (col >> 6) & 15, d = col & 63;
          if (t3 == 0)      qb[((size_t)h * S + row) * HD + d] = f2bf_hw(v * QSCALE);
          else if (t3 == 1) kb[((size_t)h * S + row) * HD + d] = f2bf_hw(v);
          else              vtb[((size_t)h * HD + d) * S + row] = f2bf_hw(v);
        }
      }
}

// ---------------- GEMM BN=64 variant (fp32 out): for O-proj --------
__global__ __launch_bounds__(256) void gemm_bt_n64(const ushort_t* __restrict__ A,
                                                   const ushort_t* __restrict__ B,
                                                   int M, int N, int K,
                                                   float* __restrict__ Cf) {
  __shared__ ushort_t sA[128 * 64];
  __shared__ ushort_t sB[64 * 64];
  const int t = threadIdx.x;
  const int lane = t & 63, w = t >> 6;
  const int wr = w >> 1, wc = w & 1;
  const int lin = blockIdx.y * gridDim.x + blockIdx.x;
  const int cpx = (gridDim.x * gridDim.y) >> 3;
  const int swz = (lin & 7) * cpx + (lin >> 3);
  const int rA0 = (swz / gridDim.x) * 128, rB0 = (swz % gridDim.x) * 64;

  f32x4 acc[4][2];
#pragma unroll
  for (int m = 0; m < 4; ++m)
#pragma unroll
    for (int n = 0; n < 2; ++n) acc[m][n] = (f32x4){0.f, 0.f, 0.f, 0.f};

  const int srow = t >> 3;
  const int scol = (t & 7) * 8;
  const int ldsbase = w * 512;

  for (int k0 = 0; k0 < K; k0 += 64) {
#pragma unroll
    for (int i = 0; i < 4; ++i) {
      int r = i * 32 + srow;
      int kc = scol ^ ((r & 7) << 3);
      gl2lds16(&A[(size_t)(rA0 + r) * K + k0 + kc], &sA[i * 2048 + ldsbase]);
    }
#pragma unroll
    for (int i = 0; i < 2; ++i) {
      int r = i * 32 + srow;
      int kc = scol ^ ((r & 7) << 3);
      gl2lds16(&B[(size_t)(rB0 + r) * K + k0 + kc], &sB[i * 2048 + ldsbase]);
    }
    __syncthreads();
#pragma unroll
    for (int ks = 0; ks < 2; ++ks) {
      const int kk = ks * 32 + (lane >> 4) * 8;
      bf16x8 af[4], bfr[2];
#pragma unroll
      for (int m = 0; m < 4; ++m) {
        int row = wr * 64 + m * 16 + (lane & 15);
        af[m] = *(const bf16x8*)&sA[row * 64 + (kk ^ ((row & 7) << 3))];
      }
#pragma unroll
      for (int n = 0; n < 2; ++n) {
        int row = wc * 32 + n * 16 + (lane & 15);
        bfr[n] = *(const bf16x8*)&sB[row * 64 + (kk ^ ((row & 7) << 3))];
      }
#pragma unroll
      for (int m = 0; m < 4; ++m)
#pragma unroll
        for (int n = 0; n < 2; ++n)
          acc[m][n] = __builtin_amdgcn_mfma_f32_16x16x32_bf16(af[m], bfr[n], acc[m][n], 0, 0, 0);
    }
    __syncthreads();
  }

#pragma unroll
  for (int m = 0; m < 4; ++m)
#pragma unroll
    for (int n = 0; n < 2; ++n)
#pragma unroll
      for (int r = 0; r < 4; ++r) {
        int row = rA0 + wr * 64 + m * 16 + (lane >> 4) * 4 + r;
        int col = rB0 + wc * 32 + n * 16 + (lane & 15);
        Cf[(size_t)row * N + col] = acc[m][n][r];
      }
}

// ---------------- flash attention core (shared by full / split variants) -----------------
// KVSPLIT: 1 = full KV per block (writes bf16 aob directly), 2 = half KV per block
// (writes fp32 numerators Op + denominators Lp; combined by attn_combine). Fixed-reference
// softmax (p = 2^s) makes split partials exactly combinable: (A0+A1)/(l0+l1).
template <int KVSPLIT>
__global__ __launch_bounds__(512) void attn_fwd(const ushort_t* __restrict__ qb,
                                                const ushort_t* __restrict__ kb,
                                                const ushort_t* __restrict__ vtb,
                                                ushort_t* __restrict__ aob,
                                                float* __restrict__ Op,
                                                float* __restrict__ Lp) {
  constexpr int NBUF = (KVSPLIT == 1) ? 3 : 2;
  __shared__ ushort_t sK[NBUF][64 * 64];
  __shared__ ushort_t sV[NBUF][64 * 64];  // V transposed: [d][kv]
  __shared__ ushort_t sP[8][16 * 64];     // per-wave P tile
  const int t = threadIdx.x, lane = t & 63, w = t >> 6;  // 8 waves
  // XCD swizzle: nwg = 512*KVSPLIT, nwg/8 contiguous per XCD -> 2 whole heads per XCD
  const int f = blockIdx.x;
  const int sidx = (f & 7) * (64 * KVSPLIT) + (f >> 3);
  int h, split, q0;
  if constexpr (KVSPLIT == 1) {
    h = sidx >> 5; split = 0; q0 = (sidx & 31) * 128;
  } else {
    h = sidx >> 6; split = (sidx >> 5) & 1; q0 = (sidx & 31) * 128;
  }
  const ushort_t* qh = qb + (size_t)h * S * HD;
  const ushort_t* kh = kb + (size_t)h * S * HD;
  const ushort_t* vh = vtb + (size_t)h * HD * S;
  const int kvbase = split * (S / KVSPLIT);

  // Q fragments in registers (already scaled by 0.125*log2e)
  bf16x8 qf[2];
  {
    int qr = q0 + w * 16 + (lane & 15);
    const ushort_t* p = &qh[(size_t)qr * HD + (lane >> 4) * 8];
    qf[0] = *(const bf16x8*)p;
    qf[1] = *(const bf16x8*)(p + 32);
  }
  f32x4 acc[4];
#pragma unroll
  for (int n = 0; n < 4; ++n) acc[n] = (f32x4){0.f, 0.f, 0.f, 0.f};
  float lsum[4] = {0.f, 0.f, 0.f, 0.f};

  const int srow = t >> 3;                  // 0..63
  const int scol = (t & 7) * 8;
  const int kc = scol ^ ((srow & 7) << 3);  // pre-swizzled global source
  const int ldsbase = w * 512;
  const int kk0 = (lane >> 4) * 8;

  auto stage = [&](int buf, int kv0) {
    gl2lds16(&kh[(size_t)(kvbase + kv0 + srow) * HD + kc], &sK[buf][ldsbase]);
    gl2lds16(&vh[(size_t)srow * S + kvbase + kv0 + kc], &sV[buf][ldsbase]);
  };

  constexpr int NT = (S / KVSPLIT) / 64;
  stage(0, 0);
  if constexpr (KVSPLIT == 1) stage(1, 64);

  for (int ti = 0; ti < NT; ++ti) {
    const int buf = ti % NBUF;
    if constexpr (KVSPLIT == 1) {
      if (ti < NT - 1) asm volatile("s_waitcnt vmcnt(2)" ::: "memory");
      else             asm volatile("s_waitcnt vmcnt(0)" ::: "memory");
    } else {
      asm volatile("s_waitcnt vmcnt(0)" ::: "memory");
    }
    __builtin_amdgcn_sched_barrier(0);
    __builtin_amdgcn_s_barrier();  // tile-ti visible everywhere; next-stage buf reader-free

    if constexpr (KVSPLIT == 1) {
      if (ti + 2 < NT) stage((ti + 2) % 3, (ti + 2) * 64);
    } else {
      if (ti + 1 < NT) stage((ti + 1) & 1, (ti + 1) * 64);
    }

    const ushort_t* Kb = &sK[buf][0];
    const ushort_t* Vb = &sV[buf][0];

    // S-tile = Q K^T  (16 q x 64 k per wave), log2 domain
    f32x4 sc[4];
    __builtin_amdgcn_s_setprio(1);
#pragma unroll
    for (int nt = 0; nt < 4; ++nt) {
      sc[nt] = (f32x4){0.f, 0.f, 0.f, 0.f};
      int row = nt * 16 + (lane & 15);
#pragma unroll
      for (int ks = 0; ks < 2; ++ks) {
        int kk = ks * 32 + kk0;
        bf16x8 kf = *(const bf16x8*)&Kb[row * 64 + (kk ^ ((row & 7) << 3))];
        sc[nt] = __builtin_amdgcn_mfma_f32_16x16x32_bf16(qf[ks], kf, sc[nt], 0, 0, 0);
      }
    }
    __builtin_amdgcn_s_setprio(0);

    // fixed-reference softmax: p = 2^s
    float p[4][4];
#pragma unroll
    for (int r = 0; r < 4; ++r) {
      float ps = 0.f;
#pragma unroll
      for (int nt = 0; nt < 4; ++nt) {
        float pv = EXP2(sc[nt][r]);
        p[nt][r] = pv;
        ps += pv;
      }
      lsum[r] += ps;
    }
    // P -> per-wave LDS (swizzled), then read back as A-fragments
    const int prow_base = (lane >> 4) * 4;
#pragma unroll
    for (int nt = 0; nt < 4; ++nt) {
      int col = nt * 16 + (lane & 15);
#pragma unroll
      for (int r = 0; r < 4; ++r) {
        int row = prow_base + r;
        sP[w][row * 64 + (col ^ ((row & 7) << 3))] = f2bf_hw(p[nt][r]);
      }
    }
    bf16x8 pf[2];
    {
      int row = lane & 15;
#pragma unroll
      for (int ks = 0; ks < 2; ++ks) {
        int kk = ks * 32 + kk0;
        pf[ks] = *(const bf16x8*)&sP[w][row * 64 + (kk ^ ((row & 7) << 3))];
      }
    }
    // O += P V
    __builtin_amdgcn_s_setprio(1);
#pragma unroll
    for (int nt = 0; nt < 4; ++nt) {
      int row = nt * 16 + (lane & 15);
#pragma unroll
      for (int ks = 0; ks < 2; ++ks) {
        int kk = ks * 32 + kk0;
        bf16x8 vf = *(const bf16x8*)&Vb[row * 64 + (kk ^ ((row & 7) << 3))];
        acc[nt] = __builtin_amdgcn_mfma_f32_16x16x32_bf16(pf[ks], vf, acc[nt], 0, 0, 0);
      }
    }
    __builtin_amdgcn_s_setprio(0);
  }
  // epilogue
  float lred[4];
#pragma unroll
  for (int r = 0; r < 4; ++r) {
    float l = lsum[r];
    l += __shfl_xor(l, 1);
    l += __shfl_xor(l, 2);
    l += __shfl_xor(l, 4);
    l += __shfl_xor(l, 8);
    lred[r] = l;
  }
  if constexpr (KVSPLIT == 1) {
#pragma unroll
    for (int nt = 0; nt < 4; ++nt)
#pragma unroll
      for (int r = 0; r < 4; ++r) {
        int row = q0 + w * 16 + (lane >> 4) * 4 + r;
        int col = h * HD + nt * 16 + (lane & 15);
        aob[(size_t)row * DMODEL + col] = f2bf_hw(acc[nt][r] / lred[r]);
      }
  } else {
    float* Os = Op + (size_t)split * S * DMODEL;
#pragma unroll
    for (int nt = 0; nt < 4; ++nt)
#pragma unroll
      for (int r = 0; r < 4; ++r) {
        int row = q0 + w * 16 + (lane >> 4) * 4 + r;
        int col = h * HD + nt * 16 + (lane & 15);
        Os[(size_t)row * DMODEL + col] = acc[nt][r];  // undivided numerator
      }
    if ((lane & 15) == 0) {
#pragma unroll
      for (int r = 0; r < 4; ++r) {
        int row = q0 + w * 16 + (lane >> 4) * 4 + r;
        Lp[((size_t)split * NH + h) * S + row] = lred[r];
      }
    }
  }
}

// ---------------- split combine: aob = (A0 + A1) / (l0 + l1), bf16 ----------------
__global__ __launch_bounds__(256) void attn_combine(const float* __restrict__ Op,
                                                    const float* __restrict__ Lp,
                                                    ushort_t* __restrict__ aob) {
  int i = blockIdx.x * 256 + threadIdx.x;  // one float4-group of columns
  int s = i >> 8;             // 256 groups of 4 per row
  int c4 = (i & 255) * 4;
  int h = c4 >> 6;
  const float4 a0 = *(const float4*)&Op[(size_t)s * DMODEL + c4];
  const float4 a1 = *(const float4*)&Op[(size_t)S * DMODEL + (size_t)s * DMODEL + c4];
  float l = Lp[(size_t)h * S + s] + Lp[(size_t)(NH + h) * S + s];
  float inv = 1.0f / l;
  ushort4 o;
  o.x = f2bf_hw((a0.x + a1.x) * inv);
  o.y = f2bf_hw((a0.y + a1.y) * inv);
  o.z = f2bf_hw((a0.z + a1.z) * inv);
  o.w = f2bf_hw((a0.w + a1.w) * inv);
  *(ushort4*)&aob[(size_t)s * DMODEL + c4] = o;
}

extern "C" void kernel_launch(void* const* d_in, const int* in_sizes, int n_in,
                              void* d_out, int out_size, void* d_ws, size_t ws_size,
                              hipStream_t stream) {
  const float* x = (const float*)d_in[0];
  const float* wqkv = (const float*)d_in[1];
  const float* wo = (const float*)d_in[2];
  float* out = (float*)d_out;
  char* ws = (char*)d_ws;
  const size_t MB = 1024ull * 1024ull;
  ushort_t* xb  = (ushort_t*)(ws);             // x bf16          [4096][1024]  8MB
  ushort_t* wqb = (ushort_t*)(ws + 8 * MB);    // w_qkv bf16      [3072][1024]  6MB
  ushort_t* wob = (ushort_t*)(ws + 14 * MB);   // w_o bf16        [1024][1024]  2MB
  ushort_t* qb  = (ushort_t*)(ws + 16 * MB);   // Q  [16][4096][64]             8MB
  ushort_t* kb  = (ushort_t*)(ws + 24 * MB);   // K  [16][4096][64]             8MB
  ushort_t* vtb = (ushort_t*)(ws + 32 * MB);   // V^T [16][64][4096]            8MB
  ushort_t* aob = (ushort_t*)(ws + 40 * MB);   // attn out bf16 [4096][1024]    8MB
  float* Op = (float*)(ws + 48 * MB);          // split numerators [2][4096][1024] f32 32MB
  float* Lp = (float*)(ws + 80 * MB);          // split denominators [2][16][4096] 512KB

  cvt_f32_bf16<<<(S * DMODEL / 4 + 255) / 256, 256, 0, stream>>>(x, xb, S * DMODEL / 4);
  cvt_f32_bf16<<<(3 * DMODEL * DMODEL / 4 + 255) / 256, 256, 0, stream>>>(wqkv, wqb, 3 * DMODEL * DMODEL / 4);
  cvt_f32_bf16<<<(DMODEL * DMODEL / 4 + 255) / 256, 256, 0, stream>>>(wo, wob, DMODEL * DMODEL / 4);

  dim3 g1(3 * DMODEL / 128, S / 128);
  gemm_bt<1><<<g1, 256, 0, stream>>>(xb, wqb, S, 3 * DMODEL, DMODEL, nullptr, qb, kb, vtb);

  if (ws_size >= 81 * MB) {
    attn_fwd<2><<<dim3(1024), 512, 0, stream>>>(qb, kb, vtb, nullptr, Op, Lp);
    attn_combine<<<dim3(S * DMODEL / 4 / 256), 256, 0, stream>>>(Op, Lp, aob);
  } else {
    attn_fwd<1><<<dim3(512), 512, 0, stream>>>(qb, kb, vtb, aob, nullptr, nullptr);
  }

  dim3 g2(DMODEL / 64, S / 128);
  gemm_bt_n64<<<g2, 256, 0, stream>>>(aob, wob, S, DMODEL, DMODEL, out);
}

// Round 14
// 174.079 us; speedup vs baseline: 1.0678x; 1.0678x over previous
//
#include <hip/hip_runtime.h>

typedef __bf16 bf16x8 __attribute__((ext_vector_type(8)));
typedef __bf16 bf16x4 __attribute__((ext_vector_type(4)));
typedef short shortx4 __attribute__((ext_vector_type(4)));
typedef float f32x4 __attribute__((ext_vector_type(4)));
typedef unsigned short ushort_t;
typedef unsigned int uint_t;

constexpr int S = 4096, DMODEL = 1024, NH = 16, HD = 64;
// softmax scale folded with log2(e): scores come out of QK^T already in log2 domain
#define QSCALE 0.18033688011112042f  // 0.125 * log2(e)

#if __has_builtin(__builtin_amdgcn_exp2f)
#define EXP2(x) __builtin_amdgcn_exp2f(x)
#else
#define EXP2(x) exp2f(x)
#endif

__device__ inline ushort_t f2bf(float f) {
  uint_t u = __builtin_bit_cast(uint_t, f);
  u = u + 0x7FFFu + ((u >> 16) & 1u);  // round-to-nearest-even
  return (ushort_t)(u >> 16);
}

__device__ inline ushort_t f2bf_hw(float f) {
  __bf16 h = (__bf16)f;  // v_cvt RNE on gfx950
  return __builtin_bit_cast(ushort_t, h);
}

// 16x16x16 bf16 MFMA: prefer the HW instruction (legacy _1k builtin); else emulate with
// zero-padded 16x16x32 (k-slot g*8+j, j<4 carries kv=g*4+j on BOTH operands -> identical).
__device__ inline f32x4 mfma16_bf16(bf16x4 a, bf16x4 b, f32x4 c) {
#if __has_builtin(__builtin_amdgcn_mfma_f32_16x16x16bf16_1k)
  return __builtin_amdgcn_mfma_f32_16x16x16bf16_1k(
      __builtin_bit_cast(shortx4, a), __builtin_bit_cast(shortx4, b), c, 0, 0, 0);
#else
  bf16x8 a8 = {a[0], a[1], a[2], a[3], (__bf16)0.f, (__bf16)0.f, (__bf16)0.f, (__bf16)0.f};
  bf16x8 b8 = {b[0], b[1], b[2], b[3], (__bf16)0.f, (__bf16)0.f, (__bf16)0.f, (__bf16)0.f};
  return __builtin_amdgcn_mfma_f32_16x16x32_bf16(a8, b8, c, 0, 0, 0);
#endif
}

__device__ inline void gl2lds16(const ushort_t* g, ushort_t* l) {
  __builtin_amdgcn_global_load_lds(
      (const __attribute__((address_space(1))) unsigned int*)g,
      (__attribute__((address_space(3))) unsigned int*)l, 16, 0, 0);
}

// ---------------- fused fp32 -> bf16 conversion (x, w_qkv, w_o in one launch) ------------
constexpr int N4_X = S * DMODEL / 4;            // 1048576
constexpr int N4_WQ = 3 * DMODEL * DMODEL / 4;  // 786432
constexpr int N4_WO = DMODEL * DMODEL / 4;      // 262144
__global__ __launch_bounds__(256) void cvt_all(const float* __restrict__ x,
                                               const float* __restrict__ wqkv,
                                               const float* __restrict__ wo,
                                               ushort_t* __restrict__ xb,
                                               ushort_t* __restrict__ wqb,
                                               ushort_t* __restrict__ wob) {
  int i = blockIdx.x * 256 + threadIdx.x;
  const float* src;
  ushort_t* dst;
  int off;
  if (i < N4_X) { src = x; dst = xb; off = i; }
  else if (i < N4_X + N4_WQ) { src = wqkv; dst = wqb; off = i - N4_X; }
  else if (i < N4_X + N4_WQ + N4_WO) { src = wo; dst = wob; off = i - N4_X - N4_WQ; }
  else return;
  float4 f = reinterpret_cast<const float4*>(src)[off];
  ushort4 o;
  o.x = f2bf(f.x); o.y = f2bf(f.y); o.z = f2bf(f.z); o.w = f2bf(f.w);
  reinterpret_cast<ushort4*>(dst)[off] = o;
}

// ---------------- GEMM: C[M][N] = A[M][K] * B[N][K]^T (both row-major [rows][K], bf16) ----
template <int EPI>
__global__ __launch_bounds__(256) void gemm_bt(const ushort_t* __restrict__ A,
                                               const ushort_t* __restrict__ B,
                                               int M, int N, int K,
                                               float* __restrict__ Cf,
                                               ushort_t* __restrict__ qb,
                                               ushort_t* __restrict__ kb,
                                               ushort_t* __restrict__ vtb) {
  __shared__ ushort_t sA[128 * 64];
  __shared__ ushort_t sB[128 * 64];
  const int t = threadIdx.x;
  const int lane = t & 63, w = t >> 6;
  const int wr = w >> 1, wc = w & 1;
  const int lin = blockIdx.y * gridDim.x + blockIdx.x;
  const int cpx = (gridDim.x * gridDim.y) >> 3;
  const int swz = (lin & 7) * cpx + (lin >> 3);
  const int rA0 = (swz / gridDim.x) * 128, rB0 = (swz % gridDim.x) * 128;

  f32x4 acc[4][4];
#pragma unroll
  for (int m = 0; m < 4; ++m)
#pragma unroll
    for (int n = 0; n < 4; ++n) acc[m][n] = (f32x4){0.f, 0.f, 0.f, 0.f};

  const int srow = t >> 3;
  const int scol = (t & 7) * 8;
  const int ldsbase = w * 512;

  for (int k0 = 0; k0 < K; k0 += 64) {
#pragma unroll
    for (int i = 0; i < 4; ++i) {
      int r = i * 32 + srow;
      int kc = scol ^ ((r & 7) << 3);
      gl2lds16(&A[(size_t)(rA0 + r) * K + k0 + kc], &sA[i * 2048 + ldsbase]);
    }
#pragma unroll
    for (int i = 0; i < 4; ++i) {
      int r = i * 32 + srow;
      int kc = scol ^ ((r & 7) << 3);
      gl2lds16(&B[(size_t)(rB0 + r) * K + k0 + kc], &sB[i * 2048 + ldsbase]);
    }
    __syncthreads();
#pragma unroll
    for (int ks = 0; ks < 2; ++ks) {
      const int kk = ks * 32 + (lane >> 4) * 8;
      bf16x8 af[4], bfr[4];
#pragma unroll
      for (int m = 0; m < 4; ++m) {
        int row = wr * 64 + m * 16 + (lane & 15);
        af[m] = *(const bf16x8*)&sA[row * 64 + (kk ^ ((row & 7) << 3))];
      }
#pragma unroll
      for (int n = 0; n < 4; ++n) {
        int row = wc * 64 + n * 16 + (lane & 15);
        bfr[n] = *(const bf16x8*)&sB[row * 64 + (kk ^ ((row & 7) << 3))];
      }
#pragma unroll
      for (int m = 0; m < 4; ++m)
#pragma unroll
        for (int n = 0; n < 4; ++n)
          acc[m][n] = __builtin_amdgcn_mfma_f32_16x16x32_bf16(af[m], bfr[n], acc[m][n], 0, 0, 0);
    }
    __syncthreads();
  }

#pragma unroll
  for (int m = 0; m < 4; ++m)
#pragma unroll
    for (int n = 0; n < 4; ++n)
#pragma unroll
      for (int r = 0; r < 4; ++r) {
        int row = rA0 + wr * 64 + m * 16 + (lane >> 4) * 4 + r;
        int col = rB0 + wc * 64 + n * 16 + (lane & 15);
        float v = acc[m][n][r];
        if constexpr (EPI == 0) {
          Cf[(size_t)row * N + col] = v;
        } else {
          int t3 = col >> 10, h = (col >> 6) & 15, d = col & 63;
          if (t3 == 0)      qb[((size_t)h * S + row) * HD + d] = f2bf_hw(v * QSCALE);
          else if (t3 == 1) kb[((size_t)h * S + row) * HD + d] = f2bf_hw(v);
          else              vtb[((size_t)h * HD + d) * S + row] = f2bf_hw(v);
        }
      }
}

// ---------------- GEMM BN=64 variant (fp32 out): for O-proj --------
__global__ __launch_bounds__(256) void gemm_bt_n64(const ushort_t* __restrict__ A,
                                                   const ushort_t* __restrict__ B,
                                                   int M, int N, int K,
                                                   float* __restrict__ Cf) {
  __shared__ ushort_t sA[128 * 64];
  __shared__ ushort_t sB[64 * 64];
  const int t = threadIdx.x;
  const int lane = t & 63, w = t >> 6;
  const int wr = w >> 1, wc = w & 1;
  const int lin = blockIdx.y * gridDim.x + blockIdx.x;
  const int cpx = (gridDim.x * gridDim.y) >> 3;
  const int swz = (lin & 7) * cpx + (lin >> 3);
  const int rA0 = (swz / gridDim.x) * 128, rB0 = (swz % gridDim.x) * 64;

  f32x4 acc[4][2];
#pragma unroll
  for (int m = 0; m < 4; ++m)
#pragma unroll
    for (int n = 0; n < 2; ++n) acc[m][n] = (f32x4){0.f, 0.f, 0.f, 0.f};

  const int srow = t >> 3;
  const int scol = (t & 7) * 8;
  const int ldsbase = w * 512;

  for (int k0 = 0; k0 < K; k0 += 64) {
#pragma unroll
    for (int i = 0; i < 4; ++i) {
      int r = i * 32 + srow;
      int kc = scol ^ ((r & 7) << 3);
      gl2lds16(&A[(size_t)(rA0 + r) * K + k0 + kc], &sA[i * 2048 + ldsbase]);
    }
#pragma unroll
    for (int i = 0; i < 2; ++i) {
      int r = i * 32 + srow;
      int kc = scol ^ ((r & 7) << 3);
      gl2lds16(&B[(size_t)(rB0 + r) * K + k0 + kc], &sB[i * 2048 + ldsbase]);
    }
    __syncthreads();
#pragma unroll
    for (int ks = 0; ks < 2; ++ks) {
      const int kk = ks * 32 + (lane >> 4) * 8;
      bf16x8 af[4], bfr[2];
#pragma unroll
      for (int m = 0; m < 4; ++m) {
        int row = wr * 64 + m * 16 + (lane & 15);
        af[m] = *(const bf16x8*)&sA[row * 64 + (kk ^ ((row & 7) << 3))];
      }
#pragma unroll
      for (int n = 0; n < 2; ++n) {
        int row = wc * 32 + n * 16 + (lane & 15);
        bfr[n] = *(const bf16x8*)&sB[row * 64 + (kk ^ ((row & 7) << 3))];
      }
#pragma unroll
      for (int m = 0; m < 4; ++m)
#pragma unroll
        for (int n = 0; n < 2; ++n)
          acc[m][n] = __builtin_amdgcn_mfma_f32_16x16x32_bf16(af[m], bfr[n], acc[m][n], 0, 0, 0);
    }
    __syncthreads();
  }

#pragma unroll
  for (int m = 0; m < 4; ++m)
#pragma unroll
    for (int n = 0; n < 2; ++n)
#pragma unroll
      for (int r = 0; r < 4; ++r) {
        int row = rA0 + wr * 64 + m * 16 + (lane >> 4) * 4 + r;
        int col = rB0 + wc * 32 + n * 16 + (lane & 15);
        Cf[(size_t)row * N + col] = acc[m][n][r];
      }
}

// ---------------- flash attention: swapped QK^T, in-register P, K=16 PV ------------------
// QK^T computed SWAPPED: sc[nt] = mfma(kf, qf) -> lane (g,l15) holds
// S[kv = nt*16 + g*4 + r][q = l15] (R3-verified mapping). For the 16x16x16 MFMA the
// A-fragment k-mapping is k = g*4 + j, so P-as-produced feeds PV DIRECTLY from registers:
// pfrag[c][j] = 2^sc[c][j]. No sP LDS roundtrip (-16 ds_write, -2 ds_read, -120cyc chain,
// -32KB LDS). V^T B-fragments become 16 ds_read_b64. Scalar per-lane lsum (q = l15);
// epilogue redistributes 1/l via 4 shuffles (output rows are q = g*4+r per C-layout).
// Pipeline: R11's 3-buf single-barrier counted-vmcnt; T1 XCD swizzle (2 heads/XCD).
__global__ __launch_bounds__(512) void attn_fwd(const ushort_t* __restrict__ qb,
                                                const ushort_t* __restrict__ kb,
                                                const ushort_t* __restrict__ vtb,
                                                ushort_t* __restrict__ aob) {
  __shared__ ushort_t sK[3][64 * 64];
  __shared__ ushort_t sV[3][64 * 64];  // V transposed: [d][kv]
  const int t = threadIdx.x, lane = t & 63, w = t >> 6;  // 8 waves
  // XCD swizzle: grid 512 (1-D), 8 XCDs, 64 blocks/XCD -> 2 heads per XCD
  const int f = blockIdx.x;
  const int sidx = (f & 7) * 64 + (f >> 3);  // bijective (512 % 8 == 0)
  const int h = sidx >> 5;
  const int q0 = (sidx & 31) * 128;
  const ushort_t* qh = qb + (size_t)h * S * HD;
  const ushort_t* kh = kb + (size_t)h * S * HD;
  const ushort_t* vh = vtb + (size_t)h * HD * S;

  const int l15 = lane & 15, g = lane >> 4;
  const int kk0 = g * 8;

  // Q as B-fragment: lane holds Q[q0 + w*16 + l15][k = ks*32 + g*8 + j] (pre-scaled)
  bf16x8 qf[2];
  {
    const ushort_t* p = &qh[(size_t)(q0 + w * 16 + l15) * HD + kk0];
    qf[0] = *(const bf16x8*)p;
    qf[1] = *(const bf16x8*)(p + 32);
  }
  f32x4 acc[4];  // O[q = w*16 + g*4 + r][d = nt*16 + l15]
#pragma unroll
  for (int n = 0; n < 4; ++n) acc[n] = (f32x4){0.f, 0.f, 0.f, 0.f};
  float lsum = 0.f;  // scalar: partial denominator of q = l15 over this lane's kv slots

  // staging: 512 threads cover one 64x64 tile in a single pass (1 load each for K and V)
  const int srow = t >> 3;                  // 0..63
  const int scol = (t & 7) * 8;             // col (elems)
  const int kc = scol ^ ((srow & 7) << 3);  // pre-swizzled global source
  const int ldsbase = w * 512;              // wave-uniform base; + lane*8 == srow*64+scol

  auto stage = [&](int buf, int kv0) {
    gl2lds16(&kh[(size_t)(kv0 + srow) * HD + kc], &sK[buf][ldsbase]);
    gl2lds16(&vh[(size_t)srow * S + kv0 + kc], &sV[buf][ldsbase]);
  };

  constexpr int NT = S / 64;
  stage(0, 0);
  stage(1, 64);

  for (int ti = 0; ti < NT; ++ti) {
    const int buf = ti % 3;
    // own tile-ti loads done (outstanding at loop top: stage(ti)=2, stage(ti+1)=2)
    if (ti < NT - 1) asm volatile("s_waitcnt vmcnt(2)" ::: "memory");
    else             asm volatile("s_waitcnt vmcnt(0)" ::: "memory");
    __builtin_amdgcn_sched_barrier(0);
    __builtin_amdgcn_s_barrier();  // tile-ti visible everywhere; buf[(ti+2)%3] reader-free

    if (ti + 2 < NT) stage((ti + 2) % 3, (ti + 2) * 64);

    const ushort_t* Kb = &sK[buf][0];
    const ushort_t* Vb = &sV[buf][0];

    // swapped S-tile: sc[nt][r] = S[kv = nt*16 + g*4 + r][q = l15], log2 domain
    f32x4 sc[4];
    __builtin_amdgcn_s_setprio(1);
#pragma unroll
    for (int nt = 0; nt < 4; ++nt) {
      sc[nt] = (f32x4){0.f, 0.f, 0.f, 0.f};
      int row = nt * 16 + l15;  // K row (kv), fragment-indexed by l15
#pragma unroll
      for (int ks = 0; ks < 2; ++ks) {
        int kk = ks * 32 + kk0;
        bf16x8 kf = *(const bf16x8*)&Kb[row * 64 + (kk ^ ((row & 7) << 3))];
        sc[nt] = __builtin_amdgcn_mfma_f32_16x16x32_bf16(kf, qf[ks], sc[nt], 0, 0, 0);
      }
    }
    __builtin_amdgcn_s_setprio(0);

    // fixed-reference softmax (p = 2^s) + pack P fragments in-register
    bf16x4 pfrag[4];
    float ps = 0.f;
#pragma unroll
    for (int c = 0; c < 4; ++c) {
      float p0 = EXP2(sc[c][0]), p1 = EXP2(sc[c][1]);
      float p2 = EXP2(sc[c][2]), p3 = EXP2(sc[c][3]);
      ps += (p0 + p1) + (p2 + p3);
      pfrag[c] = (bf16x4){(__bf16)p0, (__bf16)p1, (__bf16)p2, (__bf16)p3};
    }
    lsum += ps;

    // O += P V: A = pfrag (rows q=l15, k = g*4+j), B = V^T rows d, k = kv
    __builtin_amdgcn_s_setprio(1);
#pragma unroll
    for (int nt = 0; nt < 4; ++nt) {
      int row = nt * 16 + l15;  // d row
      const int rsw = (row & 7) << 3;
#pragma unroll
      for (int c = 0; c < 4; ++c) {
        int col = (c * 16 + g * 4) ^ rsw;  // 4-elem aligned; XOR flips bits >=3 only
        bf16x4 vf = *(const bf16x4*)&Vb[row * 64 + col];
        acc[nt] = mfma16_bf16(pfrag[c], vf, acc[nt]);
      }
    }
    __builtin_amdgcn_s_setprio(0);
  }
  // epilogue: lsum holds partials for q=l15; reduce over the 4 g-groups, then shuffle the
  // reciprocal to the output layout (rows q = g*4 + r)
  float l = lsum;
  l += __shfl_xor(l, 16);
  l += __shfl_xor(l, 32);
  float inv = 1.0f / l;  // valid at lanes with l15 = q
  float linv[4];
#pragma unroll
  for (int r = 0; r < 4; ++r) linv[r] = __shfl(inv, g * 4 + r);
#pragma unroll
  for (int nt = 0; nt < 4; ++nt)
#pragma unroll
    for (int r = 0; r < 4; ++r) {
      int row = q0 + w * 16 + g * 4 + r;
      int col = h * HD + nt * 16 + l15;
      aob[(size_t)row * DMODEL + col] = f2bf_hw(acc[nt][r] * linv[r]);
    }
}

extern "C" void kernel_launch(void* const* d_in, const int* in_sizes, int n_in,
                              void* d_out, int out_size, void* d_ws, size_t ws_size,
                              hipStream_t stream) {
  const float* x = (const float*)d_in[0];
  const float* wqkv = (const float*)d_in[1];
  const float* wo = (const float*)d_in[2];
  float* out = (float*)d_out;
  char* ws = (char*)d_ws;
  const size_t MB = 1024ull * 1024ull;
  ushort_t* xb  = (ushort_t*)(ws);             // x bf16          [4096][1024]  8MB
  ushort_t* wqb = (ushort_t*)(ws + 8 * MB);    // w_qkv bf16      [3072][1024]  6MB
  ushort_t* wob = (ushort_t*)(ws + 14 * MB);   // w_o bf16        [1024][1024]  2MB
  ushort_t* qb  = (ushort_t*)(ws + 16 * MB);   // Q  [16][4096][64]             8MB
  ushort_t* kb  = (ushort_t*)(ws + 24 * MB);   // K  [16][4096][64]             8MB
  ushort_t* vtb = (ushort_t*)(ws + 32 * MB);   // V^T [16][64][4096]            8MB
  ushort_t* aob = (ushort_t*)(ws + 40 * MB);   // attn out bf16 [4096][1024]    8MB

  cvt_all<<<(N4_X + N4_WQ + N4_WO + 255) / 256, 256, 0, stream>>>(x, wqkv, wo, xb, wqb, wob);

  dim3 g1(3 * DMODEL / 128, S / 128);
  gemm_bt<1><<<g1, 256, 0, stream>>>(xb, wqb, S, 3 * DMODEL, DMODEL, nullptr, qb, kb, vtb);

  attn_fwd<<<dim3(512), 512, 0, stream>>>(qb, kb, vtb, aob);

  dim3 g2(DMODEL / 64, S / 128);
  gemm_bt_n64<<<g2, 256, 0, stream>>>(aob, wob, S, DMODEL, DMODEL, out);
}

// Round 15
// 166.745 us; speedup vs baseline: 1.1147x; 1.0440x over previous
//
#include <hip/hip_runtime.h>

typedef __bf16 bf16x8 __attribute__((ext_vector_type(8)));
typedef float f32x4 __attribute__((ext_vector_type(4)));
typedef unsigned short ushort_t;
typedef unsigned int uint_t;

constexpr int S = 4096, DMODEL = 1024, NH = 16, HD = 64;
// softmax scale folded with log2(e): scores come out of QK^T already in log2 domain
#define QSCALE 0.18033688011112042f  // 0.125 * log2(e)

#if __has_builtin(__builtin_amdgcn_exp2f)
#define EXP2(x) __builtin_amdgcn_exp2f(x)
#else
#define EXP2(x) exp2f(x)
#endif

__device__ inline ushort_t f2bf(float f) {
  uint_t u = __builtin_bit_cast(uint_t, f);
  u = u + 0x7FFFu + ((u >> 16) & 1u);  // round-to-nearest-even
  return (ushort_t)(u >> 16);
}

__device__ inline ushort_t f2bf_hw(float f) {
  __bf16 h = (__bf16)f;  // v_cvt RNE on gfx950
  return __builtin_bit_cast(ushort_t, h);
}

__device__ inline void gl2lds16(const ushort_t* g, ushort_t* l) {
  __builtin_amdgcn_global_load_lds(
      (const __attribute__((address_space(1))) unsigned int*)g,
      (__attribute__((address_space(3))) unsigned int*)l, 16, 0, 0);
}

// ---------------- fused fp32 -> bf16 conversion (x, w_qkv, w_o in one launch) ------------
constexpr int N4_X = S * DMODEL / 4;            // 1048576
constexpr int N4_WQ = 3 * DMODEL * DMODEL / 4;  // 786432
constexpr int N4_WO = DMODEL * DMODEL / 4;      // 262144
__global__ __launch_bounds__(256) void cvt_all(const float* __restrict__ x,
                                               const float* __restrict__ wqkv,
                                               const float* __restrict__ wo,
                                               ushort_t* __restrict__ xb,
                                               ushort_t* __restrict__ wqb,
                                               ushort_t* __restrict__ wob) {
  int i = blockIdx.x * 256 + threadIdx.x;
  const float* src;
  ushort_t* dst;
  int off;
  if (i < N4_X) { src = x; dst = xb; off = i; }
  else if (i < N4_X + N4_WQ) { src = wqkv; dst = wqb; off = i - N4_X; }
  else if (i < N4_X + N4_WQ + N4_WO) { src = wo; dst = wob; off = i - N4_X - N4_WQ; }
  else return;
  float4 f = reinterpret_cast<const float4*>(src)[off];
  ushort4 o;
  o.x = f2bf(f.x); o.y = f2bf(f.y); o.z = f2bf(f.z); o.w = f2bf(f.w);
  reinterpret_cast<ushort4*>(dst)[off] = o;
}

// ---------------- GEMM: C[M][N] = A[M][K] * B[N][K]^T (both row-major [rows][K], bf16) ----
template <int EPI>
__global__ __launch_bounds__(256) void gemm_bt(const ushort_t* __restrict__ A,
                                               const ushort_t* __restrict__ B,
                                               int M, int N, int K,
                                               float* __restrict__ Cf,
                                               ushort_t* __restrict__ qb,
                                               ushort_t* __restrict__ kb,
                                               ushort_t* __restrict__ vtb) {
  __shared__ ushort_t sA[128 * 64];
  __shared__ ushort_t sB[128 * 64];
  const int t = threadIdx.x;
  const int lane = t & 63, w = t >> 6;
  const int wr = w >> 1, wc = w & 1;
  const int lin = blockIdx.y * gridDim.x + blockIdx.x;
  const int cpx = (gridDim.x * gridDim.y) >> 3;
  const int swz = (lin & 7) * cpx + (lin >> 3);
  const int rA0 = (swz / gridDim.x) * 128, rB0 = (swz % gridDim.x) * 128;

  f32x4 acc[4][4];
#pragma unroll
  for (int m = 0; m < 4; ++m)
#pragma unroll
    for (int n = 0; n < 4; ++n) acc[m][n] = (f32x4){0.f, 0.f, 0.f, 0.f};

  const int srow = t >> 3;
  const int scol = (t & 7) * 8;
  const int ldsbase = w * 512;

  for (int k0 = 0; k0 < K; k0 += 64) {
#pragma unroll
    for (int i = 0; i < 4; ++i) {
      int r = i * 32 + srow;
      int kc = scol ^ ((r & 7) << 3);
      gl2lds16(&A[(size_t)(rA0 + r) * K + k0 + kc], &sA[i * 2048 + ldsbase]);
    }
#pragma unroll
    for (int i = 0; i < 4; ++i) {
      int r = i * 32 + srow;
      int kc = scol ^ ((r & 7) << 3);
      gl2lds16(&B[(size_t)(rB0 + r) * K + k0 + kc], &sB[i * 2048 + ldsbase]);
    }
    __syncthreads();
#pragma unroll
    for (int ks = 0; ks < 2; ++ks) {
      const int kk = ks * 32 + (lane >> 4) * 8;
      bf16x8 af[4], bfr[4];
#pragma unroll
      for (int m = 0; m < 4; ++m) {
        int row = wr * 64 + m * 16 + (lane & 15);
        af[m] = *(const bf16x8*)&sA[row * 64 + (kk ^ ((row & 7) << 3))];
      }
#pragma unroll
      for (int n = 0; n < 4; ++n) {
        int row = wc * 64 + n * 16 + (lane & 15);
        bfr[n] = *(const bf16x8*)&sB[row * 64 + (kk ^ ((row & 7) << 3))];
      }
#pragma unroll
      for (int m = 0; m < 4; ++m)
#pragma unroll
        for (int n = 0; n < 4; ++n)
          acc[m][n] = __builtin_amdgcn_mfma_f32_16x16x32_bf16(af[m], bfr[n], acc[m][n], 0, 0, 0);
    }
    __syncthreads();
  }

#pragma unroll
  for (int m = 0; m < 4; ++m)
#pragma unroll
    for (int n = 0; n < 4; ++n)
#pragma unroll
      for (int r = 0; r < 4; ++r) {
        int row = rA0 + wr * 64 + m * 16 + (lane >> 4) * 4 + r;
        int col = rB0 + wc * 64 + n * 16 + (lane & 15);
        float v = acc[m][n][r];
        if constexpr (EPI == 0) {
          Cf[(size_t)row * N + col] = v;
        } else {
          int t3 = col >> 10, h = (col >> 6) & 15, d = col & 63;
          if (t3 == 0)      qb[((size_t)h * S + row) * HD + d] = f2bf_hw(v * QSCALE);
          else if (t3 == 1) kb[((size_t)h * S + row) * HD + d] = f2bf_hw(v);
          else              vtb[((size_t)h * HD + d) * S + row] = f2bf_hw(v);
        }
      }
}

// ---------------- GEMM BN=64 variant (fp32 out): for O-proj --------
__global__ __launch_bounds__(256) void gemm_bt_n64(const ushort_t* __restrict__ A,
                                                   const ushort_t* __restrict__ B,
                                                   int M, int N, int K,
                                                   float* __restrict__ Cf) {
  __shared__ ushort_t sA[128 * 64];
  __shared__ ushort_t sB[64 * 64];
  const int t = threadIdx.x;
  const int lane = t & 63, w = t >> 6;
  const int wr = w >> 1, wc = w & 1;
  const int lin = blockIdx.y * gridDim.x + blockIdx.x;
  const int cpx = (gridDim.x * gridDim.y) >> 3;
  const int swz = (lin & 7) * cpx + (lin >> 3);
  const int rA0 = (swz / gridDim.x) * 128, rB0 = (swz % gridDim.x) * 64;

  f32x4 acc[4][2];
#pragma unroll
  for (int m = 0; m < 4; ++m)
#pragma unroll
    for (int n = 0; n < 2; ++n) acc[m][n] = (f32x4){0.f, 0.f, 0.f, 0.f};

  const int srow = t >> 3;
  const int scol = (t & 7) * 8;
  const int ldsbase = w * 512;

  for (int k0 = 0; k0 < K; k0 += 64) {
#pragma unroll
    for (int i = 0; i < 4; ++i) {
      int r = i * 32 + srow;
      int kc = scol ^ ((r & 7) << 3);
      gl2lds16(&A[(size_t)(rA0 + r) * K + k0 + kc], &sA[i * 2048 + ldsbase]);
    }
#pragma unroll
    for (int i = 0; i < 2; ++i) {
      int r = i * 32 + srow;
      int kc = scol ^ ((r & 7) << 3);
      gl2lds16(&B[(size_t)(rB0 + r) * K + k0 + kc], &sB[i * 2048 + ldsbase]);
    }
    __syncthreads();
#pragma unroll
    for (int ks = 0; ks < 2; ++ks) {
      const int kk = ks * 32 + (lane >> 4) * 8;
      bf16x8 af[4], bfr[2];
#pragma unroll
      for (int m = 0; m < 4; ++m) {
        int row = wr * 64 + m * 16 + (lane & 15);
        af[m] = *(const bf16x8*)&sA[row * 64 + (kk ^ ((row & 7) << 3))];
      }
#pragma unroll
      for (int n = 0; n < 2; ++n) {
        int row = wc * 32 + n * 16 + (lane & 15);
        bfr[n] = *(const bf16x8*)&sB[row * 64 + (kk ^ ((row & 7) << 3))];
      }
#pragma unroll
      for (int m = 0; m < 4; ++m)
#pragma unroll
        for (int n = 0; n < 2; ++n)
          acc[m][n] = __builtin_amdgcn_mfma_f32_16x16x32_bf16(af[m], bfr[n], acc[m][n], 0, 0, 0);
    }
    __syncthreads();
  }

#pragma unroll
  for (int m = 0; m < 4; ++m)
#pragma unroll
    for (int n = 0; n < 2; ++n)
#pragma unroll
      for (int r = 0; r < 4; ++r) {
        int row = rA0 + wr * 64 + m * 16 + (lane >> 4) * 4 + r;
        int col = rB0 + wc * 32 + n * 16 + (lane & 15);
        Cf[(size_t)row * N + col] = acc[m][n][r];
      }
}

// ---------------- flash attention: QBLK=128, 8 waves, 3-buf, single barrier (R11-best) ---
// Iteration: vmcnt(2) [own tile-ti K/V done; stage(ti+1) stays in flight] -> barrier
// [everyone's tile-ti visible AND buf[(ti+2)%3] reader-free] -> stage(ti+2) -> compute.
// T1 XCD swizzle (2 heads/XCD: K/V L2-resident, FETCH 12MB). Fixed-reference softmax
// (p = 2^s, scores O(+-10) in log2 domain -> shift-free is safe by ~100 binades).
__global__ __launch_bounds__(512) void attn_fwd(const ushort_t* __restrict__ qb,
                                                const ushort_t* __restrict__ kb,
                                                const ushort_t* __restrict__ vtb,
                                                ushort_t* __restrict__ aob) {
  __shared__ ushort_t sK[3][64 * 64];
  __shared__ ushort_t sV[3][64 * 64];  // V transposed: [d][kv]
  __shared__ ushort_t sP[8][16 * 64];  // per-wave P tile
  const int t = threadIdx.x, lane = t & 63, w = t >> 6;  // 8 waves
  const int f = blockIdx.x;
  const int sidx = (f & 7) * 64 + (f >> 3);  // bijective (512 % 8 == 0)
  const int h = sidx >> 5;
  const int q0 = (sidx & 31) * 128;
  const ushort_t* qh = qb + (size_t)h * S * HD;
  const ushort_t* kh = kb + (size_t)h * S * HD;
  const ushort_t* vh = vtb + (size_t)h * HD * S;

  // Q fragments in registers: wave owns 16 q rows (already scaled by 0.125*log2e)
  bf16x8 qf[2];
  {
    int qr = q0 + w * 16 + (lane & 15);
    const ushort_t* p = &qh[(size_t)qr * HD + (lane >> 4) * 8];
    qf[0] = *(const bf16x8*)p;
    qf[1] = *(const bf16x8*)(p + 32);
  }
  f32x4 acc[4];
#pragma unroll
  for (int n = 0; n < 4; ++n) acc[n] = (f32x4){0.f, 0.f, 0.f, 0.f};
  float lsum[4] = {0.f, 0.f, 0.f, 0.f};  // per-lane partial denominators

  const int srow = t >> 3;                  // 0..63
  const int scol = (t & 7) * 8;             // col (elems)
  const int kc = scol ^ ((srow & 7) << 3);  // pre-swizzled global source
  const int ldsbase = w * 512;              // wave-uniform base; + lane*8 == srow*64+scol
  const int kk0 = (lane >> 4) * 8;

  auto stage = [&](int buf, int kv0) {
    gl2lds16(&kh[(size_t)(kv0 + srow) * HD + kc], &sK[buf][ldsbase]);
    gl2lds16(&vh[(size_t)srow * S + kv0 + kc], &sV[buf][ldsbase]);
  };

  constexpr int NT = S / 64;
  stage(0, 0);
  stage(1, 64);

  for (int ti = 0; ti < NT; ++ti) {
    const int buf = ti % 3;
    if (ti < NT - 1) asm volatile("s_waitcnt vmcnt(2)" ::: "memory");
    else             asm volatile("s_waitcnt vmcnt(0)" ::: "memory");
    __builtin_amdgcn_sched_barrier(0);
    __builtin_amdgcn_s_barrier();  // tile-ti visible everywhere; buf[(ti+2)%3] reader-free

    if (ti + 2 < NT) stage((ti + 2) % 3, (ti + 2) * 64);

    const ushort_t* Kb = &sK[buf][0];
    const ushort_t* Vb = &sV[buf][0];

    // S-tile = Q K^T  (16 q x 64 k per wave), log2 domain
    f32x4 sc[4];
    __builtin_amdgcn_s_setprio(1);
#pragma unroll
    for (int nt = 0; nt < 4; ++nt) {
      sc[nt] = (f32x4){0.f, 0.f, 0.f, 0.f};
      int row = nt * 16 + (lane & 15);
#pragma unroll
      for (int ks = 0; ks < 2; ++ks) {
        int kk = ks * 32 + kk0;
        bf16x8 kf = *(const bf16x8*)&Kb[row * 64 + (kk ^ ((row & 7) << 3))];
        sc[nt] = __builtin_amdgcn_mfma_f32_16x16x32_bf16(qf[ks], kf, sc[nt], 0, 0, 0);
      }
    }
    __builtin_amdgcn_s_setprio(0);

    // fixed-reference softmax: p = 2^s
    float p[4][4];
#pragma unroll
    for (int r = 0; r < 4; ++r) {
      float ps = 0.f;
#pragma unroll
      for (int nt = 0; nt < 4; ++nt) {
        float pv = EXP2(sc[nt][r]);
        p[nt][r] = pv;
        ps += pv;
      }
      lsum[r] += ps;  // per-lane partial; reduced once in epilogue
    }
    // P -> per-wave LDS (swizzled), then read back as A-fragments
    const int prow_base = (lane >> 4) * 4;
#pragma unroll
    for (int nt = 0; nt < 4; ++nt) {
      int col = nt * 16 + (lane & 15);
#pragma unroll
      for (int r = 0; r < 4; ++r) {
        int row = prow_base + r;
        sP[w][row * 64 + (col ^ ((row & 7) << 3))] = f2bf_hw(p[nt][r]);
      }
    }
    bf16x8 pf[2];
    {
      int row = lane & 15;
#pragma unroll
      for (int ks = 0; ks < 2; ++ks) {
        int kk = ks * 32 + kk0;
        pf[ks] = *(const bf16x8*)&sP[w][row * 64 + (kk ^ ((row & 7) << 3))];
      }
    }
    // O += P V   (V^T staged: B-fragment reads contiguous)
    __builtin_amdgcn_s_setprio(1);
#pragma unroll
    for (int nt = 0; nt < 4; ++nt) {
      int row = nt * 16 + (lane & 15);
#pragma unroll
      for (int ks = 0; ks < 2; ++ks) {
        int kk = ks * 32 + kk0;
        bf16x8 vf = *(const bf16x8*)&Vb[row * 64 + (kk ^ ((row & 7) << 3))];
        acc[nt] = __builtin_amdgcn_mfma_f32_16x16x32_bf16(pf[ks], vf, acc[nt], 0, 0, 0);
      }
    }
    __builtin_amdgcn_s_setprio(0);
  }
  // epilogue: reduce per-lane partial sums across the 16-lane row group, write out
  float linv[4];
#pragma unroll
  for (int r = 0; r < 4; ++r) {
    float l = lsum[r];
    l += __shfl_xor(l, 1);
    l += __shfl_xor(l, 2);
    l += __shfl_xor(l, 4);
    l += __shfl_xor(l, 8);
    linv[r] = 1.0f / l;
  }
#pragma unroll
  for (int nt = 0; nt < 4; ++nt)
#pragma unroll
    for (int r = 0; r < 4; ++r) {
      int row = q0 + w * 16 + (lane >> 4) * 4 + r;
      int col = h * HD + nt * 16 + (lane & 15);
      aob[(size_t)row * DMODEL + col] = f2bf_hw(acc[nt][r] * linv[r]);
    }
}

extern "C" void kernel_launch(void* const* d_in, const int* in_sizes, int n_in,
                              void* d_out, int out_size, void* d_ws, size_t ws_size,
                              hipStream_t stream) {
  const float* x = (const float*)d_in[0];
  const float* wqkv = (const float*)d_in[1];
  const float* wo = (const float*)d_in[2];
  float* out = (float*)d_out;
  char* ws = (char*)d_ws;
  const size_t MB = 1024ull * 1024ull;
  ushort_t* xb  = (ushort_t*)(ws);             // x bf16          [4096][1024]  8MB
  ushort_t* wqb = (ushort_t*)(ws + 8 * MB);    // w_qkv bf16      [3072][1024]  6MB
  ushort_t* wob = (ushort_t*)(ws + 14 * MB);   // w_o bf16        [1024][1024]  2MB
  ushort_t* qb  = (ushort_t*)(ws + 16 * MB);   // Q  [16][4096][64]             8MB
  ushort_t* kb  = (ushort_t*)(ws + 24 * MB);   // K  [16][4096][64]             8MB
  ushort_t* vtb = (ushort_t*)(ws + 32 * MB);   // V^T [16][64][4096]            8MB
  ushort_t* aob = (ushort_t*)(ws + 40 * MB);   // attn out bf16 [4096][1024]    8MB

  cvt_all<<<(N4_X + N4_WQ + N4_WO + 255) / 256, 256, 0, stream>>>(x, wqkv, wo, xb, wqb, wob);

  dim3 g1(3 * DMODEL / 128, S / 128);
  gemm_bt<1><<<g1, 256, 0, stream>>>(xb, wqb, S, 3 * DMODEL, DMODEL, nullptr, qb, kb, vtb);

  attn_fwd<<<dim3(512), 512, 0, stream>>>(qb, kb, vtb, aob);

  dim3 g2(DMODEL / 64, S / 128);
  gemm_bt_n64<<<g2, 256, 0, stream>>>(aob, wob, S, DMODEL, DMODEL, out);
}